// Round 7
// baseline (567.730 us; speedup 1.0000x reference)
//
#include <hip/hip_runtime.h>
#include <math.h>

#define NN 4096
#define WW 12
#define HH 256
#define PP 10
#define EE 131072
#define HS 262144
#define HMASK (HS-1)
#define TS 192           // table intervals (193 sample points) -> 2.37 MB, L2-resident
#define TA 8.0f          // table half-domain: a in [-TA, TA]
#define RS 22            // ring stride: 12 init cols + 10 pred cols (append, no overwrite)

typedef __attribute__((ext_vector_type(8))) short short8v;   // 8 x bf16 (A/B frag)
typedef __attribute__((ext_vector_type(4))) float f32x4;     // C/D frag

__device__ __forceinline__ float fast_tanh(float x){
  float e = __expf(2.0f*x);
  return 1.0f - 2.0f/(e+1.0f);   // exact identity (e^2x-1)/(e^2x+1)
}
__device__ __forceinline__ float fast_sigmoid(float x){
  return 1.0f/(1.0f+__expf(-x));
}
__device__ __forceinline__ unsigned short f2bf(float f){     // RNE fp32->bf16
  union{float f; unsigned u;} v; v.f = f;
  unsigned r = v.u + 0x7FFF + ((v.u>>16)&1);
  return (unsigned short)(r>>16);
}
__device__ __forceinline__ float bf2f(unsigned short h){
  union{unsigned u; float f;} v; v.u = ((unsigned)h)<<16; return v.f;
}
__device__ __forceinline__ void cvt8(const float4 x0, const float4 x1,
                                     short8v* oh, short8v* ol){
  float f[8] = {x0.x,x0.y,x0.z,x0.w,x1.x,x1.y,x1.z,x1.w};
  short h8[8], l8[8];
  #pragma unroll
  for (int j = 0; j < 8; ++j){
    unsigned short hh_ = f2bf(f[j]);
    h8[j] = (short)hh_;
    l8[j] = (short)f2bf(f[j] - bf2f(hh_));
  }
  *oh = *(short8v*)h8; *ol = *(short8v*)l8;
}

// ---------------- setup kernels ----------------

__global__ void k_init(const float* __restrict__ x, int* keys, int* midx,
                       float* deg, int* cnt, float* ring, float* hA, int* count){
  int i = blockIdx.x*256 + threadIdx.x;
  if (i < HS){ keys[i] = -1; midx[i] = -1; }
  if (i < NN){ deg[i] = 0.0f; cnt[i] = 0; }
  if (i < NN*WW){ int n = i/WW, w = i - n*WW; ring[n*RS + w] = x[i]; }
  if (i < NN*HH) hA[i] = 0.0f;
  if (i == 0) *count = 0;
}

// dedupe: numpy fancy assignment => last (max-index) edge wins per (src,dst)
__global__ void k_insert(const int* __restrict__ ei, int* keys, int* midx){
  int e = blockIdx.x*256 + threadIdx.x;
  if (e >= EE) return;
  int key = ei[e]*NN + ei[EE+e];
  unsigned h = (((unsigned)key)*2654435761u >> 14) & HMASK;
  for(;;){
    int k = keys[h];
    if (k == key){ atomicMax(&midx[h], e); return; }
    if (k == -1){
      int old = atomicCAS(&keys[h], -1, key);
      if (old == -1 || old == key){ atomicMax(&midx[h], e); return; }
    }
    h = (h+1) & HMASK;
  }
}

__global__ void k_compact(const int* __restrict__ ei, const float* __restrict__ ew,
                          const int* __restrict__ keys, const int* __restrict__ midx,
                          int* wsrc, int* wdst, float* wwt,
                          float* deg, int* cnt, int* count){
  int e = blockIdx.x*256 + threadIdx.x;
  if (e >= EE) return;
  int src = ei[e], dst = ei[EE+e];
  int key = src*NN + dst;
  unsigned h = (((unsigned)key)*2654435761u >> 14) & HMASK;
  while (keys[h] != key) h = (h+1) & HMASK;
  if (midx[h] == e){            // this edge is the winner for (src,dst)
    int p = atomicAdd(count, 1);
    wsrc[p] = src; wdst[p] = dst; wwt[p] = ew[e];
    atomicAdd(&deg[src], ew[e]);   // deg = row-sum of deduped adj (self-loop +1 later)
    atomicAdd(&cnt[dst], 1);       // CSR histogram keyed by dst (L uses adj^T)
  }
}

__global__ __launch_bounds__(1024) void k_scan(const int* __restrict__ cnt,
                                               int* row_start, int* fill){
  __shared__ int sd[NN];
  int tid = threadIdx.x;
  for (int i = tid; i < NN; i += 1024) sd[i] = cnt[i];
  __syncthreads();
  for (int off = 1; off < NN; off <<= 1){
    int v[4];
    #pragma unroll
    for (int r = 0; r < 4; ++r){
      int i = tid + r*1024;
      v[r] = (i >= off) ? sd[i-off] : 0;
    }
    __syncthreads();
    #pragma unroll
    for (int r = 0; r < 4; ++r) sd[tid + r*1024] += v[r];
    __syncthreads();
  }
  for (int i = tid; i < NN; i += 1024){
    int incl = sd[i];
    row_start[i+1] = incl;
    fill[i] = incl - cnt[i];   // exclusive prefix = scatter cursor
  }
  if (tid == 0) row_start[0] = 0;
}

// scatter + inline coef = wwt * d[src] * d[dst], d = 1/sqrt(deg+1)
__global__ void k_scatter(const int* __restrict__ wsrc, const int* __restrict__ wdst,
                          const float* __restrict__ wwt, const float* __restrict__ deg,
                          int* fill, int* csr_src, float* csr_cf,
                          const int* __restrict__ count){
  int p = blockIdx.x*256 + threadIdx.x;
  if (p >= *count) return;
  int s = wsrc[p], d = wdst[p];
  float c = wwt[p] * (1.0f/sqrtf(deg[s]+1.0f)) * (1.0f/sqrtf(deg[d]+1.0f));
  int pos = atomicAdd(&fill[d], 1);
  csr_src[pos] = s;
  csr_cf[pos] = c;
}

// table build: tab[w][s][h] = sum_c tanh(a_s*gw[c]) * ta_w[w*256+c, h]
__global__ __launch_bounds__(256) void k_tab(const float* __restrict__ gcn_w,
                                             const float* __restrict__ ta_w,
                                             float* __restrict__ tab){
  __shared__ float As[32][64];
  __shared__ float Bs[32][64];
  __shared__ float gws[256];
  int tid = threadIdx.x;
  int n0 = blockIdx.x*64;        // h tile
  int m0 = blockIdx.y*64;        // sample tile
  int w  = blockIdx.z;
  gws[tid] = gcn_w[tid];
  __syncthreads();
  float acc[4][4] = {};
  int tm = tid >> 4, tn = tid & 15;
  const float astep = 2.0f*TA/TS;
  for (int k0 = 0; k0 < 256; k0 += 32){
    #pragma unroll
    for (int r = 0; r < 2; ++r){
      int f = tid + r*256;
      int kk = f >> 4, n4 = (f & 15)*4;
      *(float4*)&Bs[kk][n4] = *(const float4*)&ta_w[(w*256 + k0+kk)*HH + n0 + n4];
    }
    {
      int kk = tid >> 3;
      int mb = (tid & 7)*8;
      float gw = gws[k0 + kk];
      #pragma unroll
      for (int i2 = 0; i2 < 8; ++i2){
        float a = -TA + (float)(m0 + mb + i2)*astep;
        As[kk][mb+i2] = fast_tanh(a*gw);
      }
    }
    __syncthreads();
    #pragma unroll
    for (int kk = 0; kk < 32; ++kk){
      float4 a4 = *(float4*)&As[kk][tm*4];
      float4 b4 = *(float4*)&Bs[kk][tn*4];
      float a[4] = {a4.x,a4.y,a4.z,a4.w};
      float b[4] = {b4.x,b4.y,b4.z,b4.w};
      #pragma unroll
      for (int i = 0; i < 4; ++i)
        #pragma unroll
        for (int j = 0; j < 4; ++j)
          acc[i][j] = fmaf(a[i], b[j], acc[i][j]);
    }
    __syncthreads();
  }
  #pragma unroll
  for (int i = 0; i < 4; ++i){
    int row = m0 + tm*4 + i;
    if (row <= TS){
      #pragma unroll
      for (int j = 0; j < 4; ++j)
        tab[((size_t)w*(TS+1) + row)*HH + n0 + tn*4 + j] = acc[i][j];
    }
  }
}

// pack GRU weights into MFMA B-fragment order, bf16 hi/lo planes (run once).
// groups g: 0=r, 1=z, 2=xn (K 0..255), 3=hn (K 256..511).
// layout: [ks(16)][g(4)][ct(16)][lane(64)][8 shorts]
__global__ void k_wpack(const float* __restrict__ w_ih, const float* __restrict__ w_hh,
                        short* __restrict__ wp_hi, short* __restrict__ wp_lo){
  int idx = blockIdx.x*256 + threadIdx.x;       // 65536 fragment-octets
  int lane = idx & 63;
  int rest = idx >> 6;
  int ct = rest & 15; rest >>= 4;
  int g  = rest & 3;
  int ks = rest >> 2;
  int col = ct*16 + (lane & 15);
  int kb  = ks*32 + (lane >> 4)*8;
  short hi[8], lo[8];
  #pragma unroll
  for (int j = 0; j < 8; ++j){
    int k = kb + j;
    float v;
    if      (g == 0) v = (k < 256) ? w_ih[col*HH + k]        : w_hh[col*HH + k - 256];
    else if (g == 1) v = (k < 256) ? w_ih[(256+col)*HH + k]  : w_hh[(256+col)*HH + k - 256];
    else if (g == 2) v = (k < 256) ? w_ih[(512+col)*HH + k]  : 0.0f;
    else             v = (k < 256) ? 0.0f                    : w_hh[(512+col)*HH + k - 256];
    unsigned short h = f2bf(v);
    hi[j] = (short)h;
    lo[j] = (short)f2bf(v - bf2f(h));
  }
  *(short8v*)&wp_hi[(size_t)idx*8] = *(short8v*)hi;
  *(short8v*)&wp_lo[(size_t)idx*8] = *(short8v*)lo;
}

// ---------------- the per-step kernel ----------------
// One dispatch per step; 128 blocks x 1024 threads; block owns nodes
// [32b, 32b+32) END-TO-END, no cross-block deps. Each wave computes
// 32 rows x 16 cols (2 row-frags share every B-fragment load -> halves
// the L2 weight-request bytes vs 1 row-frag/wave).
__global__ __launch_bounds__(1024) void k_step(
    const int* __restrict__ rowst, const int* __restrict__ csr_src,
    const float* __restrict__ csr_cf, const float* __restrict__ deg,
    float* __restrict__ ring, const float* __restrict__ tab,
    const float* __restrict__ ta_b,
    const float* __restrict__ hc, float* __restrict__ hnb,
    const short* __restrict__ wp_hi, const short* __restrict__ wp_lo,
    const float* __restrict__ b_ih, const float* __restrict__ b_hh,
    const float* __restrict__ out_w, const float* __restrict__ out_b,
    float* __restrict__ out, int s){

  // 260-float row stride: stride%32 = 4 banks -> low-order aliasing only
  __shared__ __align__(16) float t_pad[32][260];
  __shared__ __align__(16) float h_pad[32][260];
  __shared__ int   sidx[32][12];
  __shared__ float sfrac[32][12];

  const int tid = threadIdx.x;
  const int n0 = blockIdx.x*32;
  const int wv = tid >> 6, lane = tid & 63;

  // ---- stage hc -> LDS (two float4 per thread), CSR gather -> sidx/sfrac ----
  {
    int row = tid >> 5;           // 0..31
    int c0 = (tid & 31)*8;        // 0..248
    const float* hr = hc + (size_t)(n0+row)*HH + c0;
    *(float4*)&h_pad[row][c0]   = *(const float4*)(hr);
    *(float4*)&h_pad[row][c0+4] = *(const float4*)(hr+4);
  }
  if (tid < 384){
    int r = tid/12, w = tid - r*12;
    int node = n0 + r;
    float dv = 1.0f/sqrtf(deg[node] + 1.0f);
    float acc0 = dv*dv*ring[(size_t)node*RS + s + w];
    int e1 = rowst[node+1];
    for (int e = rowst[node]; e < e1; ++e)
      acc0 += csr_cf[e]*ring[(size_t)csr_src[e]*RS + s + w];
    float u = (acc0 + TA) * ((float)TS/(2.0f*TA));
    u = fminf(fmaxf(u, 0.0f), (float)TS - 0.0005f);
    int i = (int)u;
    sidx[r][w] = i;
    sfrac[r][w] = u - (float)i;
  }
  __syncthreads();

  // ---- table lerp -> t (LDS): 1024 threads, 8 rows x 12 lerps each ----
  {
    int col = tid & 255;
    int r0 = (tid >> 8)*8;
    float tb = ta_b[col];
    #pragma unroll
    for (int rr = 0; rr < 8; ++rr){
      int r = r0 + rr;
      float acc0 = tb;
      #pragma unroll
      for (int w = 0; w < 12; ++w){
        const float* pj = tab + ((size_t)w*(TS+1) + sidx[r][w])*HH + col;
        float v0 = pj[0], v1 = pj[HH];
        acc0 += v0 + sfrac[r][w]*(v1 - v0);
      }
      t_pad[r][col] = acc0 > 0.0f ? acc0 : 0.0f;
    }
  }
  __syncthreads();

  // ---- GRU MFMA: wave wv owns col-tile ct=wv (16 cols) x 32 rows, K=512 ----
  f32x4 acc[4][2];
  #pragma unroll
  for (int g = 0; g < 4; ++g){
    acc[g][0] = (f32x4){0.f,0.f,0.f,0.f};
    acc[g][1] = (f32x4){0.f,0.f,0.f,0.f};
  }

  const int a_row = lane & 15, a_oct = lane >> 4;

  #pragma unroll
  for (int ks = 0; ks < 16; ++ks){
    const float* ap0 = (ks < 8) ? &t_pad[a_row][ks*32 + a_oct*8]
                                : &h_pad[a_row][(ks-8)*32 + a_oct*8];
    const float* ap1 = (ks < 8) ? &t_pad[16 + a_row][ks*32 + a_oct*8]
                                : &h_pad[16 + a_row][(ks-8)*32 + a_oct*8];
    short8v ah0, al0, ah1, al1;
    cvt8(*(const float4*)ap0, *(const float4*)(ap0+4), &ah0, &al0);
    cvt8(*(const float4*)ap1, *(const float4*)(ap1+4), &ah1, &al1);
    const int G2 = (ks < 8) ? 2 : 3;
    const size_t fb = (((size_t)ks*4)*16 + (size_t)wv)*64 + lane;
    short8v b0h = *(const short8v*)&wp_hi[(fb + (size_t)0*16*64)*8];
    short8v b0l = *(const short8v*)&wp_lo[(fb + (size_t)0*16*64)*8];
    short8v b1h = *(const short8v*)&wp_hi[(fb + (size_t)1*16*64)*8];
    short8v b1l = *(const short8v*)&wp_lo[(fb + (size_t)1*16*64)*8];
    short8v b2h = *(const short8v*)&wp_hi[(fb + (size_t)G2*16*64)*8];
    short8v b2l = *(const short8v*)&wp_lo[(fb + (size_t)G2*16*64)*8];
    acc[0][0]  = __builtin_amdgcn_mfma_f32_16x16x32_bf16(ah0, b0h, acc[0][0], 0,0,0);
    acc[0][0]  = __builtin_amdgcn_mfma_f32_16x16x32_bf16(al0, b0h, acc[0][0], 0,0,0);
    acc[0][0]  = __builtin_amdgcn_mfma_f32_16x16x32_bf16(ah0, b0l, acc[0][0], 0,0,0);
    acc[0][1]  = __builtin_amdgcn_mfma_f32_16x16x32_bf16(ah1, b0h, acc[0][1], 0,0,0);
    acc[0][1]  = __builtin_amdgcn_mfma_f32_16x16x32_bf16(al1, b0h, acc[0][1], 0,0,0);
    acc[0][1]  = __builtin_amdgcn_mfma_f32_16x16x32_bf16(ah1, b0l, acc[0][1], 0,0,0);
    acc[1][0]  = __builtin_amdgcn_mfma_f32_16x16x32_bf16(ah0, b1h, acc[1][0], 0,0,0);
    acc[1][0]  = __builtin_amdgcn_mfma_f32_16x16x32_bf16(al0, b1h, acc[1][0], 0,0,0);
    acc[1][0]  = __builtin_amdgcn_mfma_f32_16x16x32_bf16(ah0, b1l, acc[1][0], 0,0,0);
    acc[1][1]  = __builtin_amdgcn_mfma_f32_16x16x32_bf16(ah1, b1h, acc[1][1], 0,0,0);
    acc[1][1]  = __builtin_amdgcn_mfma_f32_16x16x32_bf16(al1, b1h, acc[1][1], 0,0,0);
    acc[1][1]  = __builtin_amdgcn_mfma_f32_16x16x32_bf16(ah1, b1l, acc[1][1], 0,0,0);
    acc[G2][0] = __builtin_amdgcn_mfma_f32_16x16x32_bf16(ah0, b2h, acc[G2][0], 0,0,0);
    acc[G2][0] = __builtin_amdgcn_mfma_f32_16x16x32_bf16(al0, b2h, acc[G2][0], 0,0,0);
    acc[G2][0] = __builtin_amdgcn_mfma_f32_16x16x32_bf16(ah0, b2l, acc[G2][0], 0,0,0);
    acc[G2][1] = __builtin_amdgcn_mfma_f32_16x16x32_bf16(ah1, b2h, acc[G2][1], 0,0,0);
    acc[G2][1] = __builtin_amdgcn_mfma_f32_16x16x32_bf16(al1, b2h, acc[G2][1], 0,0,0);
    acc[G2][1] = __builtin_amdgcn_mfma_f32_16x16x32_bf16(ah1, b2l, acc[G2][1], 0,0,0);
  }
  __syncthreads();   // all waves done reading t_pad before epilogue overwrites it

  // ---- epilogue: gates + h' -> global hnb + LDS (t_pad reused as h') ----
  {
    const int ecl  = lane & 15;
    const int erow = (lane >> 4)*4;
    const int col  = wv*16 + ecl;
    float br  = b_ih[col]        + b_hh[col];
    float bz  = b_ih[col + HH]   + b_hh[col + HH];
    float bxn = b_ih[col + 2*HH];
    float bhn = b_hh[col + 2*HH];
    #pragma unroll
    for (int rf = 0; rf < 2; ++rf){
      #pragma unroll
      for (int q = 0; q < 4; ++q){
        int row = rf*16 + erow + q;
        float r = fast_sigmoid(acc[0][rf][q] + br);
        float z = fast_sigmoid(acc[1][rf][q] + bz);
        float n = fast_tanh(acc[2][rf][q] + bxn + r*(acc[3][rf][q] + bhn));
        float hv = h_pad[row][col];
        float hp = (1.0f - z)*n + z*hv;
        hnb[(size_t)(n0+row)*HH + col] = hp;
        t_pad[row][col] = hp;
      }
    }
  }
  __syncthreads();

  // ---- pred: wave wv owns rows {2wv, 2wv+1}; h' . out_w + out_b ----
  {
    int row = 2*wv + (lane >> 5);
    int c0 = (lane & 31)*8;
    float sacc = 0.0f;
    #pragma unroll
    for (int j = 0; j < 2; ++j){
      float4 hv = *(const float4*)&t_pad[row][c0 + j*4];
      float4 w4 = *(const float4*)(out_w + c0 + j*4);
      sacc += hv.x*w4.x + hv.y*w4.y + hv.z*w4.z + hv.w*w4.w;
    }
    sacc += __shfl_xor(sacc, 1, 64);
    sacc += __shfl_xor(sacc, 2, 64);
    sacc += __shfl_xor(sacc, 4, 64);
    sacc += __shfl_xor(sacc, 8, 64);
    sacc += __shfl_xor(sacc, 16, 64);
    if ((lane & 31) == 0){
      float pv = sacc + out_b[0];
      out[(size_t)(n0+row)*PP + s] = pv;
      ring[(size_t)(n0+row)*RS + 12 + s] = pv;
    }
  }
}

// ---------------- launcher ----------------

extern "C" void kernel_launch(void* const* d_in, const int* in_sizes, int n_in,
                              void* d_out, int out_size, void* d_ws, size_t ws_size,
                              hipStream_t stream){
  const float* x     = (const float*)d_in[0];
  const int*   ei    = (const int*)  d_in[1];
  const float* ew    = (const float*)d_in[2];
  const float* gcn_w = (const float*)d_in[3];
  const float* ta_w  = (const float*)d_in[4];
  const float* ta_b  = (const float*)d_in[5];
  const float* w_ih  = (const float*)d_in[6];
  const float* w_hh  = (const float*)d_in[7];
  const float* b_ih  = (const float*)d_in[8];
  const float* b_hh  = (const float*)d_in[9];
  const float* out_w = (const float*)d_in[10];
  const float* out_b = (const float*)d_in[11];
  float* out = (float*)d_out;

  char* p = (char*)d_ws;
  float* tab     = (float*)p; p += (size_t)12*(TS+1)*HH*4; // 2.37 MB
  int*   keys    = (int*)p;   p += (size_t)HS*4;
  int*   midx    = (int*)p;   p += (size_t)HS*4;
  int*   wsrc    = (int*)p;   p += (size_t)EE*4;
  int*   wdst    = (int*)p;   p += (size_t)EE*4;
  float* wwt     = (float*)p; p += (size_t)EE*4;
  int*   csr_src = (int*)p;   p += (size_t)EE*4;
  float* csr_cf  = (float*)p; p += (size_t)EE*4;
  float* deg     = (float*)p; p += (size_t)NN*4;
  int*   cnt     = (int*)p;   p += (size_t)NN*4;
  int*   fill    = (int*)p;   p += (size_t)NN*4;
  int*   rowst   = (int*)p;   p += (size_t)(NN+64)*4;
  int*   count   = (int*)p;   p += 256;
  float* ring    = (float*)p; p += (size_t)NN*RS*4;
  float* hA      = (float*)p; p += (size_t)NN*HH*4;
  float* hB      = (float*)p; p += (size_t)NN*HH*4;
  short* wp_hi   = (short*)p; p += (size_t)16*4*16*64*8*2; // 1 MB
  short* wp_lo   = (short*)p; p += (size_t)16*4*16*64*8*2; // 1 MB

  k_init   <<<(NN*HH)/256, 256, 0, stream>>>(x, keys, midx, deg, cnt, ring, hA, count);
  k_insert <<<EE/256, 256, 0, stream>>>(ei, keys, midx);
  k_compact<<<EE/256, 256, 0, stream>>>(ei, ew, keys, midx, wsrc, wdst, wwt, deg, cnt, count);
  k_scan   <<<1, 1024, 0, stream>>>(cnt, rowst, fill);
  k_scatter<<<EE/256, 256, 0, stream>>>(wsrc, wdst, wwt, deg, fill, csr_src, csr_cf, count);
  k_wpack  <<<256, 256, 0, stream>>>(w_ih, w_hh, wp_hi, wp_lo);
  k_tab    <<<dim3(HH/64, (TS+64)/64, WW), 256, 0, stream>>>(gcn_w, ta_w, tab);

  for (int s = 0; s < PP; ++s){
    const float* hc  = (s & 1) ? hB : hA;
    float*       hnb = (s & 1) ? hA : hB;
    k_step<<<NN/32, 1024, 0, stream>>>(rowst, csr_src, csr_cf, deg, ring, tab,
                                       ta_b, hc, hnb, wp_hi, wp_lo,
                                       b_ih, b_hh, out_w, out_b, out, s);
  }
}

// Round 8
// 365.889 us; speedup vs baseline: 1.5516x; 1.5516x over previous
//
#include <hip/hip_runtime.h>
#include <math.h>

#define NN 4096
#define WW 12
#define HH 256
#define PP 10
#define EE 131072
#define HS 262144
#define HMASK (HS-1)
#define TS 192           // table intervals (193 sample points) -> 2.37 MB, L2-resident
#define TA 8.0f          // table half-domain: a in [-TA, TA]
#define RS 22            // ring stride: 12 init cols + 10 pred cols (append, no overwrite)

typedef __attribute__((ext_vector_type(8))) short short8v;   // 8 x bf16 (A/B frag)
typedef __attribute__((ext_vector_type(4))) float f32x4;     // C/D frag

__device__ __forceinline__ float fast_tanh(float x){
  float e = __expf(2.0f*x);
  return 1.0f - 2.0f/(e+1.0f);   // exact identity (e^2x-1)/(e^2x+1)
}
__device__ __forceinline__ float fast_sigmoid(float x){
  return 1.0f/(1.0f+__expf(-x));
}
__device__ __forceinline__ unsigned short f2bf(float f){     // RNE fp32->bf16
  union{float f; unsigned u;} v; v.f = f;
  unsigned r = v.u + 0x7FFF + ((v.u>>16)&1);
  return (unsigned short)(r>>16);
}
__device__ __forceinline__ float bf2f(unsigned short h){
  union{unsigned u; float f;} v; v.u = ((unsigned)h)<<16; return v.f;
}
__device__ __forceinline__ void cvt8(const float4 x0, const float4 x1,
                                     short8v* oh, short8v* ol){
  float f[8] = {x0.x,x0.y,x0.z,x0.w,x1.x,x1.y,x1.z,x1.w};
  short h8[8], l8[8];
  #pragma unroll
  for (int j = 0; j < 8; ++j){
    unsigned short hh_ = f2bf(f[j]);
    h8[j] = (short)hh_;
    l8[j] = (short)f2bf(f[j] - bf2f(hh_));
  }
  *oh = *(short8v*)h8; *ol = *(short8v*)l8;
}

// ---------------- setup kernels ----------------

__global__ void k_init(const float* __restrict__ x, int* keys, int* midx,
                       float* deg, int* cnt, float* ring, float* hA, int* count){
  int i = blockIdx.x*256 + threadIdx.x;
  if (i < HS){ keys[i] = -1; midx[i] = -1; }
  if (i < NN){ deg[i] = 0.0f; cnt[i] = 0; }
  if (i < NN*WW){ int n = i/WW, w = i - n*WW; ring[n*RS + w] = x[i]; }
  if (i < NN*HH) hA[i] = 0.0f;
  if (i == 0) *count = 0;
}

// dedupe: numpy fancy assignment => last (max-index) edge wins per (src,dst)
__global__ void k_insert(const int* __restrict__ ei, int* keys, int* midx){
  int e = blockIdx.x*256 + threadIdx.x;
  if (e >= EE) return;
  int key = ei[e]*NN + ei[EE+e];
  unsigned h = (((unsigned)key)*2654435761u >> 14) & HMASK;
  for(;;){
    int k = keys[h];
    if (k == key){ atomicMax(&midx[h], e); return; }
    if (k == -1){
      int old = atomicCAS(&keys[h], -1, key);
      if (old == -1 || old == key){ atomicMax(&midx[h], e); return; }
    }
    h = (h+1) & HMASK;
  }
}

__global__ void k_compact(const int* __restrict__ ei, const float* __restrict__ ew,
                          const int* __restrict__ keys, const int* __restrict__ midx,
                          int* wsrc, int* wdst, float* wwt,
                          float* deg, int* cnt, int* count){
  int e = blockIdx.x*256 + threadIdx.x;
  if (e >= EE) return;
  int src = ei[e], dst = ei[EE+e];
  int key = src*NN + dst;
  unsigned h = (((unsigned)key)*2654435761u >> 14) & HMASK;
  while (keys[h] != key) h = (h+1) & HMASK;
  if (midx[h] == e){            // this edge is the winner for (src,dst)
    int p = atomicAdd(count, 1);
    wsrc[p] = src; wdst[p] = dst; wwt[p] = ew[e];
    atomicAdd(&deg[src], ew[e]);   // deg = row-sum of deduped adj (self-loop +1 later)
    atomicAdd(&cnt[dst], 1);       // CSR histogram keyed by dst (L uses adj^T)
  }
}

__global__ __launch_bounds__(1024) void k_scan(const int* __restrict__ cnt,
                                               int* row_start, int* fill){
  __shared__ int sd[NN];
  int tid = threadIdx.x;
  for (int i = tid; i < NN; i += 1024) sd[i] = cnt[i];
  __syncthreads();
  for (int off = 1; off < NN; off <<= 1){
    int v[4];
    #pragma unroll
    for (int r = 0; r < 4; ++r){
      int i = tid + r*1024;
      v[r] = (i >= off) ? sd[i-off] : 0;
    }
    __syncthreads();
    #pragma unroll
    for (int r = 0; r < 4; ++r) sd[tid + r*1024] += v[r];
    __syncthreads();
  }
  for (int i = tid; i < NN; i += 1024){
    int incl = sd[i];
    row_start[i+1] = incl;
    fill[i] = incl - cnt[i];   // exclusive prefix = scatter cursor
  }
  if (tid == 0) row_start[0] = 0;
}

// scatter + inline coef = wwt * d[src] * d[dst], d = 1/sqrt(deg+1)
__global__ void k_scatter(const int* __restrict__ wsrc, const int* __restrict__ wdst,
                          const float* __restrict__ wwt, const float* __restrict__ deg,
                          int* fill, int* csr_src, float* csr_cf,
                          const int* __restrict__ count){
  int p = blockIdx.x*256 + threadIdx.x;
  if (p >= *count) return;
  int s = wsrc[p], d = wdst[p];
  float c = wwt[p] * (1.0f/sqrtf(deg[s]+1.0f)) * (1.0f/sqrtf(deg[d]+1.0f));
  int pos = atomicAdd(&fill[d], 1);
  csr_src[pos] = s;
  csr_cf[pos] = c;
}

// table build: tab[w][s][h] = sum_c tanh(a_s*gw[c]) * ta_w[w*256+c, h]
__global__ __launch_bounds__(256) void k_tab(const float* __restrict__ gcn_w,
                                             const float* __restrict__ ta_w,
                                             float* __restrict__ tab){
  __shared__ float As[32][64];
  __shared__ float Bs[32][64];
  __shared__ float gws[256];
  int tid = threadIdx.x;
  int n0 = blockIdx.x*64;        // h tile
  int m0 = blockIdx.y*64;        // sample tile
  int w  = blockIdx.z;
  gws[tid] = gcn_w[tid];
  __syncthreads();
  float acc[4][4] = {};
  int tm = tid >> 4, tn = tid & 15;
  const float astep = 2.0f*TA/TS;
  for (int k0 = 0; k0 < 256; k0 += 32){
    #pragma unroll
    for (int r = 0; r < 2; ++r){
      int f = tid + r*256;
      int kk = f >> 4, n4 = (f & 15)*4;
      *(float4*)&Bs[kk][n4] = *(const float4*)&ta_w[(w*256 + k0+kk)*HH + n0 + n4];
    }
    {
      int kk = tid >> 3;
      int mb = (tid & 7)*8;
      float gw = gws[k0 + kk];
      #pragma unroll
      for (int i2 = 0; i2 < 8; ++i2){
        float a = -TA + (float)(m0 + mb + i2)*astep;
        As[kk][mb+i2] = fast_tanh(a*gw);
      }
    }
    __syncthreads();
    #pragma unroll
    for (int kk = 0; kk < 32; ++kk){
      float4 a4 = *(float4*)&As[kk][tm*4];
      float4 b4 = *(float4*)&Bs[kk][tn*4];
      float a[4] = {a4.x,a4.y,a4.z,a4.w};
      float b[4] = {b4.x,b4.y,b4.z,b4.w};
      #pragma unroll
      for (int i = 0; i < 4; ++i)
        #pragma unroll
        for (int j = 0; j < 4; ++j)
          acc[i][j] = fmaf(a[i], b[j], acc[i][j]);
    }
    __syncthreads();
  }
  #pragma unroll
  for (int i = 0; i < 4; ++i){
    int row = m0 + tm*4 + i;
    if (row <= TS){
      #pragma unroll
      for (int j = 0; j < 4; ++j)
        tab[((size_t)w*(TS+1) + row)*HH + n0 + tn*4 + j] = acc[i][j];
    }
  }
}

// pack GRU weights into MFMA B-fragment order, bf16 hi/lo planes (run once).
// groups g: 0=r, 1=z, 2=xn (K 0..255), 3=hn (K 256..511).
// layout: [ks(16)][g(4)][ct(16)][lane(64)][8 shorts]
__global__ void k_wpack(const float* __restrict__ w_ih, const float* __restrict__ w_hh,
                        short* __restrict__ wp_hi, short* __restrict__ wp_lo){
  int idx = blockIdx.x*256 + threadIdx.x;       // 65536 fragment-octets
  int lane = idx & 63;
  int rest = idx >> 6;
  int ct = rest & 15; rest >>= 4;
  int g  = rest & 3;
  int ks = rest >> 2;
  int col = ct*16 + (lane & 15);
  int kb  = ks*32 + (lane >> 4)*8;
  short hi[8], lo[8];
  #pragma unroll
  for (int j = 0; j < 8; ++j){
    int k = kb + j;
    float v;
    if      (g == 0) v = (k < 256) ? w_ih[col*HH + k]        : w_hh[col*HH + k - 256];
    else if (g == 1) v = (k < 256) ? w_ih[(256+col)*HH + k]  : w_hh[(256+col)*HH + k - 256];
    else if (g == 2) v = (k < 256) ? w_ih[(512+col)*HH + k]  : 0.0f;
    else             v = (k < 256) ? 0.0f                    : w_hh[(512+col)*HH + k - 256];
    unsigned short h = f2bf(v);
    hi[j] = (short)h;
    lo[j] = (short)f2bf(v - bf2f(h));
  }
  *(short8v*)&wp_hi[(size_t)idx*8] = *(short8v*)hi;
  *(short8v*)&wp_lo[(size_t)idx*8] = *(short8v*)lo;
}

// ---------------- the per-step kernel ----------------
// One dispatch per step; 256 blocks x 1024 threads (full chip); block owns
// nodes [16b, 16b+16) END-TO-END, no cross-block deps. Wave wv = col-tile wv
// (16 cols) x 16 rows. B-fragments are register double-buffered: ks+1's six
// frags load while ks's MFMAs run, hiding L2/LLC latency.
__global__ __launch_bounds__(1024, 4) void k_step(
    const int* __restrict__ rowst, const int* __restrict__ csr_src,
    const float* __restrict__ csr_cf, const float* __restrict__ deg,
    float* __restrict__ ring, const float* __restrict__ tab,
    const float* __restrict__ ta_b,
    const float* __restrict__ hc, float* __restrict__ hnb,
    const short* __restrict__ wp_hi, const short* __restrict__ wp_lo,
    const float* __restrict__ b_ih, const float* __restrict__ b_hh,
    const float* __restrict__ out_w, const float* __restrict__ out_b,
    float* __restrict__ out, int s){

  __shared__ __align__(16) float t_pad[16][260];
  __shared__ __align__(16) float h_pad[16][260];
  __shared__ int   sidx[16][12];
  __shared__ float sfrac[16][12];

  const int tid = threadIdx.x;
  const int n0 = blockIdx.x*16;
  const int wv = tid >> 6, lane = tid & 63;

  // ---- stage hc -> LDS (one float4 per thread) ----
  {
    int row = tid >> 6;           // 0..15
    int c0 = (tid & 63)*4;        // 0..252
    *(float4*)&h_pad[row][c0] = *(const float4*)(hc + (size_t)(n0+row)*HH + c0);
  }
  // ---- CSR gather: wave wv owns node n0+wv; 48 lanes = 12 w x 4 edge-groups ----
  if (lane < 48){
    int w = lane >> 2, g = lane & 3;
    int node = n0 + wv;
    float acc0 = 0.0f;
    if (g == 0){
      float dv2 = 1.0f/(deg[node] + 1.0f);     // dv*dv
      acc0 = dv2*ring[(size_t)node*RS + s + w];
    }
    int e1 = rowst[node+1];
    for (int e = rowst[node] + g; e < e1; e += 4)
      acc0 += csr_cf[e]*ring[(size_t)csr_src[e]*RS + s + w];
    acc0 += __shfl_xor(acc0, 1, 64);
    acc0 += __shfl_xor(acc0, 2, 64);
    if (g == 0){
      float u = (acc0 + TA) * ((float)TS/(2.0f*TA));
      u = fminf(fmaxf(u, 0.0f), (float)TS - 0.0005f);
      int i = (int)u;
      sidx[wv][w] = i;
      sfrac[wv][w] = u - (float)i;
    }
  }
  __syncthreads();

  // ---- table lerp -> t (LDS): 1024 threads, 4 rows x 12 lerps each ----
  {
    int col = tid & 255;
    int r0 = (tid >> 8)*4;
    float tb = ta_b[col];
    #pragma unroll
    for (int rr = 0; rr < 4; ++rr){
      int r = r0 + rr;
      float acc0 = tb;
      #pragma unroll
      for (int w = 0; w < 12; ++w){
        const float* pj = tab + ((size_t)w*(TS+1) + sidx[r][w])*HH + col;
        float v0 = pj[0], v1 = pj[HH];
        acc0 += v0 + sfrac[r][w]*(v1 - v0);
      }
      t_pad[r][col] = acc0 > 0.0f ? acc0 : 0.0f;
    }
  }
  __syncthreads();

  // ---- GRU MFMA: wave wv owns col-tile wv (16 cols) x 16 rows, K=512 ----
  // B-frags register double-buffered across ks iterations.
  f32x4 acc[4];
  #pragma unroll
  for (int g = 0; g < 4; ++g) acc[g] = (f32x4){0.f,0.f,0.f,0.f};

  const int a_row = lane & 15, a_oct = lane >> 4;
  const size_t fbase = (size_t)wv*64 + lane;   // + ks*4096 + g*1024

  short8v b0h[2], b0l[2], b1h[2], b1l[2], b2h[2], b2l[2];

#define LOADB(KS, BUF)                                                        \
  {                                                                           \
    const int G2v = ((KS) < 8) ? 2 : 3;                                       \
    const size_t fb = fbase + (size_t)(KS)*4096;                              \
    b0h[BUF] = *(const short8v*)&wp_hi[fb*8];                                 \
    b0l[BUF] = *(const short8v*)&wp_lo[fb*8];                                 \
    b1h[BUF] = *(const short8v*)&wp_hi[(fb + 1024)*8];                        \
    b1l[BUF] = *(const short8v*)&wp_lo[(fb + 1024)*8];                        \
    b2h[BUF] = *(const short8v*)&wp_hi[(fb + (size_t)G2v*1024)*8];            \
    b2l[BUF] = *(const short8v*)&wp_lo[(fb + (size_t)G2v*1024)*8];            \
  }

  LOADB(0, 0)
  #pragma unroll
  for (int ks = 0; ks < 16; ++ks){
    const int cur = ks & 1, nxt = cur ^ 1;
    if (ks < 15) LOADB(ks+1, nxt)
    const float* ap = (ks < 8) ? &t_pad[a_row][ks*32 + a_oct*8]
                               : &h_pad[a_row][(ks-8)*32 + a_oct*8];
    short8v ah, al;
    cvt8(*(const float4*)ap, *(const float4*)(ap+4), &ah, &al);
    const int G2 = (ks < 8) ? 2 : 3;
    acc[0]  = __builtin_amdgcn_mfma_f32_16x16x32_bf16(ah, b0h[cur], acc[0], 0,0,0);
    acc[0]  = __builtin_amdgcn_mfma_f32_16x16x32_bf16(al, b0h[cur], acc[0], 0,0,0);
    acc[0]  = __builtin_amdgcn_mfma_f32_16x16x32_bf16(ah, b0l[cur], acc[0], 0,0,0);
    acc[1]  = __builtin_amdgcn_mfma_f32_16x16x32_bf16(ah, b1h[cur], acc[1], 0,0,0);
    acc[1]  = __builtin_amdgcn_mfma_f32_16x16x32_bf16(al, b1h[cur], acc[1], 0,0,0);
    acc[1]  = __builtin_amdgcn_mfma_f32_16x16x32_bf16(ah, b1l[cur], acc[1], 0,0,0);
    acc[G2] = __builtin_amdgcn_mfma_f32_16x16x32_bf16(ah, b2h[cur], acc[G2], 0,0,0);
    acc[G2] = __builtin_amdgcn_mfma_f32_16x16x32_bf16(al, b2h[cur], acc[G2], 0,0,0);
    acc[G2] = __builtin_amdgcn_mfma_f32_16x16x32_bf16(ah, b2l[cur], acc[G2], 0,0,0);
  }
#undef LOADB
  __syncthreads();   // all waves done reading t_pad before epilogue overwrites it

  // ---- epilogue: gates + h' -> global hnb + LDS (t_pad reused as h') ----
  {
    const int ecl  = lane & 15;
    const int erow = (lane >> 4)*4;
    const int col  = wv*16 + ecl;
    float br  = b_ih[col]        + b_hh[col];
    float bz  = b_ih[col + HH]   + b_hh[col + HH];
    float bxn = b_ih[col + 2*HH];
    float bhn = b_hh[col + 2*HH];
    #pragma unroll
    for (int q = 0; q < 4; ++q){
      int row = erow + q;
      float r = fast_sigmoid(acc[0][q] + br);
      float z = fast_sigmoid(acc[1][q] + bz);
      float n = fast_tanh(acc[2][q] + bxn + r*(acc[3][q] + bhn));
      float hv = h_pad[row][col];
      float hp = (1.0f - z)*n + z*hv;
      hnb[(size_t)(n0+row)*HH + col] = hp;
      t_pad[row][col] = hp;
    }
  }
  __syncthreads();

  // ---- pred: wave wv owns row wv; h' . out_w + out_b -> out, ring ----
  {
    int c0 = lane*4;
    float4 hv = *(const float4*)&t_pad[wv][c0];
    float4 w4 = *(const float4*)(out_w + c0);
    float sacc = hv.x*w4.x + hv.y*w4.y + hv.z*w4.z + hv.w*w4.w;
    sacc += __shfl_xor(sacc, 1, 64);
    sacc += __shfl_xor(sacc, 2, 64);
    sacc += __shfl_xor(sacc, 4, 64);
    sacc += __shfl_xor(sacc, 8, 64);
    sacc += __shfl_xor(sacc, 16, 64);
    sacc += __shfl_xor(sacc, 32, 64);
    if (lane == 0){
      float pv = sacc + out_b[0];
      out[(size_t)(n0+wv)*PP + s] = pv;
      ring[(size_t)(n0+wv)*RS + 12 + s] = pv;
    }
  }
}

// ---------------- launcher ----------------

extern "C" void kernel_launch(void* const* d_in, const int* in_sizes, int n_in,
                              void* d_out, int out_size, void* d_ws, size_t ws_size,
                              hipStream_t stream){
  const float* x     = (const float*)d_in[0];
  const int*   ei    = (const int*)  d_in[1];
  const float* ew    = (const float*)d_in[2];
  const float* gcn_w = (const float*)d_in[3];
  const float* ta_w  = (const float*)d_in[4];
  const float* ta_b  = (const float*)d_in[5];
  const float* w_ih  = (const float*)d_in[6];
  const float* w_hh  = (const float*)d_in[7];
  const float* b_ih  = (const float*)d_in[8];
  const float* b_hh  = (const float*)d_in[9];
  const float* out_w = (const float*)d_in[10];
  const float* out_b = (const float*)d_in[11];
  float* out = (float*)d_out;

  char* p = (char*)d_ws;
  float* tab     = (float*)p; p += (size_t)12*(TS+1)*HH*4; // 2.37 MB
  int*   keys    = (int*)p;   p += (size_t)HS*4;
  int*   midx    = (int*)p;   p += (size_t)HS*4;
  int*   wsrc    = (int*)p;   p += (size_t)EE*4;
  int*   wdst    = (int*)p;   p += (size_t)EE*4;
  float* wwt     = (float*)p; p += (size_t)EE*4;
  int*   csr_src = (int*)p;   p += (size_t)EE*4;
  float* csr_cf  = (float*)p; p += (size_t)EE*4;
  float* deg     = (float*)p; p += (size_t)NN*4;
  int*   cnt     = (int*)p;   p += (size_t)NN*4;
  int*   fill    = (int*)p;   p += (size_t)NN*4;
  int*   rowst   = (int*)p;   p += (size_t)(NN+64)*4;
  int*   count   = (int*)p;   p += 256;
  float* ring    = (float*)p; p += (size_t)NN*RS*4;
  float* hA      = (float*)p; p += (size_t)NN*HH*4;
  float* hB      = (float*)p; p += (size_t)NN*HH*4;
  short* wp_hi   = (short*)p; p += (size_t)16*4*16*64*8*2; // 1 MB
  short* wp_lo   = (short*)p; p += (size_t)16*4*16*64*8*2; // 1 MB

  k_init   <<<(NN*HH)/256, 256, 0, stream>>>(x, keys, midx, deg, cnt, ring, hA, count);
  k_insert <<<EE/256, 256, 0, stream>>>(ei, keys, midx);
  k_compact<<<EE/256, 256, 0, stream>>>(ei, ew, keys, midx, wsrc, wdst, wwt, deg, cnt, count);
  k_scan   <<<1, 1024, 0, stream>>>(cnt, rowst, fill);
  k_scatter<<<EE/256, 256, 0, stream>>>(wsrc, wdst, wwt, deg, fill, csr_src, csr_cf, count);
  k_wpack  <<<256, 256, 0, stream>>>(w_ih, w_hh, wp_hi, wp_lo);
  k_tab    <<<dim3(HH/64, (TS+64)/64, WW), 256, 0, stream>>>(gcn_w, ta_w, tab);

  for (int s = 0; s < PP; ++s){
    const float* hc  = (s & 1) ? hB : hA;
    float*       hnb = (s & 1) ? hA : hB;
    k_step<<<NN/16, 1024, 0, stream>>>(rowst, csr_src, csr_cf, deg, ring, tab,
                                       ta_b, hc, hnb, wp_hi, wp_lo,
                                       b_ih, b_hh, out_w, out_b, out, s);
  }
}

// Round 9
// 364.162 us; speedup vs baseline: 1.5590x; 1.0047x over previous
//
#include <hip/hip_runtime.h>
#include <math.h>

#define NN 4096
#define WW 12
#define HH 256
#define PP 10
#define EE 131072
#define HS 262144
#define HMASK (HS-1)
#define TS 192           // table intervals (193 sample points) -> 2.37 MB, L2-resident
#define TA 8.0f          // table half-domain: a in [-TA, TA]
#define RS 22            // ring stride: 12 init cols + 10 pred cols (append, no overwrite)

typedef __attribute__((ext_vector_type(8))) short short8v;   // 8 x bf16 (A/B frag)
typedef __attribute__((ext_vector_type(4))) float f32x4;     // C/D frag

__device__ __forceinline__ float fast_tanh(float x){
  float e = __expf(2.0f*x);
  return 1.0f - 2.0f/(e+1.0f);   // exact identity (e^2x-1)/(e^2x+1)
}
__device__ __forceinline__ float fast_sigmoid(float x){
  return 1.0f/(1.0f+__expf(-x));
}
__device__ __forceinline__ unsigned short f2bf(float f){     // RNE fp32->bf16
  union{float f; unsigned u;} v; v.f = f;
  unsigned r = v.u + 0x7FFF + ((v.u>>16)&1);
  return (unsigned short)(r>>16);
}
__device__ __forceinline__ float bf2f(unsigned short h){
  union{unsigned u; float f;} v; v.u = ((unsigned)h)<<16; return v.f;
}

// ---------------- setup kernels ----------------

__global__ void k_init(const float* __restrict__ x, int* keys, int* midx,
                       float* deg, int* cnt, float* ring, float* hA, int* count){
  int i = blockIdx.x*256 + threadIdx.x;
  if (i < HS){ keys[i] = -1; midx[i] = -1; }
  if (i < NN){ deg[i] = 0.0f; cnt[i] = 0; }
  if (i < NN*WW){ int n = i/WW, w = i - n*WW; ring[n*RS + w] = x[i]; }
  if (i < NN*HH) hA[i] = 0.0f;
  if (i == 0) *count = 0;
}

// dedupe: numpy fancy assignment => last (max-index) edge wins per (src,dst)
__global__ void k_insert(const int* __restrict__ ei, int* keys, int* midx){
  int e = blockIdx.x*256 + threadIdx.x;
  if (e >= EE) return;
  int key = ei[e]*NN + ei[EE+e];
  unsigned h = (((unsigned)key)*2654435761u >> 14) & HMASK;
  for(;;){
    int k = keys[h];
    if (k == key){ atomicMax(&midx[h], e); return; }
    if (k == -1){
      int old = atomicCAS(&keys[h], -1, key);
      if (old == -1 || old == key){ atomicMax(&midx[h], e); return; }
    }
    h = (h+1) & HMASK;
  }
}

__global__ void k_compact(const int* __restrict__ ei, const float* __restrict__ ew,
                          const int* __restrict__ keys, const int* __restrict__ midx,
                          int* wsrc, int* wdst, float* wwt,
                          float* deg, int* cnt, int* count){
  int e = blockIdx.x*256 + threadIdx.x;
  if (e >= EE) return;
  int src = ei[e], dst = ei[EE+e];
  int key = src*NN + dst;
  unsigned h = (((unsigned)key)*2654435761u >> 14) & HMASK;
  while (keys[h] != key) h = (h+1) & HMASK;
  if (midx[h] == e){            // this edge is the winner for (src,dst)
    int p = atomicAdd(count, 1);
    wsrc[p] = src; wdst[p] = dst; wwt[p] = ew[e];
    atomicAdd(&deg[src], ew[e]);   // deg = row-sum of deduped adj (self-loop +1 later)
    atomicAdd(&cnt[dst], 1);       // CSR histogram keyed by dst (L uses adj^T)
  }
}

__global__ __launch_bounds__(1024) void k_scan(const int* __restrict__ cnt,
                                               int* row_start, int* fill){
  __shared__ int sd[NN];
  int tid = threadIdx.x;
  for (int i = tid; i < NN; i += 1024) sd[i] = cnt[i];
  __syncthreads();
  for (int off = 1; off < NN; off <<= 1){
    int v[4];
    #pragma unroll
    for (int r = 0; r < 4; ++r){
      int i = tid + r*1024;
      v[r] = (i >= off) ? sd[i-off] : 0;
    }
    __syncthreads();
    #pragma unroll
    for (int r = 0; r < 4; ++r) sd[tid + r*1024] += v[r];
    __syncthreads();
  }
  for (int i = tid; i < NN; i += 1024){
    int incl = sd[i];
    row_start[i+1] = incl;
    fill[i] = incl - cnt[i];   // exclusive prefix = scatter cursor
  }
  if (tid == 0) row_start[0] = 0;
}

// scatter + inline coef = wwt * d[src] * d[dst], d = 1/sqrt(deg+1)
__global__ void k_scatter(const int* __restrict__ wsrc, const int* __restrict__ wdst,
                          const float* __restrict__ wwt, const float* __restrict__ deg,
                          int* fill, int* csr_src, float* csr_cf,
                          const int* __restrict__ count){
  int p = blockIdx.x*256 + threadIdx.x;
  if (p >= *count) return;
  int s = wsrc[p], d = wdst[p];
  float c = wwt[p] * (1.0f/sqrtf(deg[s]+1.0f)) * (1.0f/sqrtf(deg[d]+1.0f));
  int pos = atomicAdd(&fill[d], 1);
  csr_src[pos] = s;
  csr_cf[pos] = c;
}

// table build: tab[w][s][h] = sum_c tanh(a_s*gw[c]) * ta_w[w*256+c, h]
__global__ __launch_bounds__(256) void k_tab(const float* __restrict__ gcn_w,
                                             const float* __restrict__ ta_w,
                                             float* __restrict__ tab){
  __shared__ float As[32][64];
  __shared__ float Bs[32][64];
  __shared__ float gws[256];
  int tid = threadIdx.x;
  int n0 = blockIdx.x*64;        // h tile
  int m0 = blockIdx.y*64;        // sample tile
  int w  = blockIdx.z;
  gws[tid] = gcn_w[tid];
  __syncthreads();
  float acc[4][4] = {};
  int tm = tid >> 4, tn = tid & 15;
  const float astep = 2.0f*TA/TS;
  for (int k0 = 0; k0 < 256; k0 += 32){
    #pragma unroll
    for (int r = 0; r < 2; ++r){
      int f = tid + r*256;
      int kk = f >> 4, n4 = (f & 15)*4;
      *(float4*)&Bs[kk][n4] = *(const float4*)&ta_w[(w*256 + k0+kk)*HH + n0 + n4];
    }
    {
      int kk = tid >> 3;
      int mb = (tid & 7)*8;
      float gw = gws[k0 + kk];
      #pragma unroll
      for (int i2 = 0; i2 < 8; ++i2){
        float a = -TA + (float)(m0 + mb + i2)*astep;
        As[kk][mb+i2] = fast_tanh(a*gw);
      }
    }
    __syncthreads();
    #pragma unroll
    for (int kk = 0; kk < 32; ++kk){
      float4 a4 = *(float4*)&As[kk][tm*4];
      float4 b4 = *(float4*)&Bs[kk][tn*4];
      float a[4] = {a4.x,a4.y,a4.z,a4.w};
      float b[4] = {b4.x,b4.y,b4.z,b4.w};
      #pragma unroll
      for (int i = 0; i < 4; ++i)
        #pragma unroll
        for (int j = 0; j < 4; ++j)
          acc[i][j] = fmaf(a[i], b[j], acc[i][j]);
    }
    __syncthreads();
  }
  #pragma unroll
  for (int i = 0; i < 4; ++i){
    int row = m0 + tm*4 + i;
    if (row <= TS){
      #pragma unroll
      for (int j = 0; j < 4; ++j)
        tab[((size_t)w*(TS+1) + row)*HH + n0 + tn*4 + j] = acc[i][j];
    }
  }
}

// pack GRU weights into MFMA B-fragment order, bf16 hi/lo planes (run once).
// groups g: 0=r, 1=z, 2=xn (K 0..255), 3=hn (K 256..511).
// layout: [ks(16)][g(4)][ct(16)][lane(64)][8 shorts]
__global__ void k_wpack(const float* __restrict__ w_ih, const float* __restrict__ w_hh,
                        short* __restrict__ wp_hi, short* __restrict__ wp_lo){
  int idx = blockIdx.x*256 + threadIdx.x;       // 65536 fragment-octets
  int lane = idx & 63;
  int rest = idx >> 6;
  int ct = rest & 15; rest >>= 4;
  int g  = rest & 3;
  int ks = rest >> 2;
  int col = ct*16 + (lane & 15);
  int kb  = ks*32 + (lane >> 4)*8;
  short hi[8], lo[8];
  #pragma unroll
  for (int j = 0; j < 8; ++j){
    int k = kb + j;
    float v;
    if      (g == 0) v = (k < 256) ? w_ih[col*HH + k]        : w_hh[col*HH + k - 256];
    else if (g == 1) v = (k < 256) ? w_ih[(256+col)*HH + k]  : w_hh[(256+col)*HH + k - 256];
    else if (g == 2) v = (k < 256) ? w_ih[(512+col)*HH + k]  : 0.0f;
    else             v = (k < 256) ? 0.0f                    : w_hh[(512+col)*HH + k - 256];
    unsigned short h = f2bf(v);
    hi[j] = (short)h;
    lo[j] = (short)f2bf(v - bf2f(h));
  }
  *(short8v*)&wp_hi[(size_t)idx*8] = *(short8v*)hi;
  *(short8v*)&wp_lo[(size_t)idx*8] = *(short8v*)lo;
}

// ---------------- the per-step kernel ----------------
// One dispatch per step; 256 blocks x 1024 threads; block owns nodes
// [16b,16b+16) END-TO-END. A-operand X=[t|h] pre-split to bf16 hi/lo ONCE
// into frag-major LDS [koct 64][row 17pad][8]; MFMA loop is then just
// 2 ds_read_b128 + 6 prefetched global 16B loads + 9 MFMAs per ks.
__global__ __launch_bounds__(1024, 4) void k_step(
    const int* __restrict__ rowst, const int* __restrict__ csr_src,
    const float* __restrict__ csr_cf, const float* __restrict__ deg,
    float* __restrict__ ring, const float* __restrict__ tab,
    const float* __restrict__ ta_b,
    const float* __restrict__ hc, float* __restrict__ hnb,
    const short* __restrict__ wp_hi, const short* __restrict__ wp_lo,
    const float* __restrict__ b_ih, const float* __restrict__ b_hh,
    const float* __restrict__ out_w, const float* __restrict__ out_b,
    float* __restrict__ out, int s){

  __shared__ __align__(16) short Xh[64][17][8];   // 17.4 KB, koct stride 272B
  __shared__ __align__(16) short Xl[64][17][8];   // (bank-spread via 17-pad)
  __shared__ __align__(16) float h_pad[16][260];  // fp32 h for epilogue + pred
  __shared__ int   sidx[16][12];
  __shared__ float sfrac[16][12];

  const int tid = threadIdx.x;
  const int n0 = blockIdx.x*16;
  const int wv = tid >> 6, lane = tid & 63;

  // ---- stage hc -> LDS fp32 + bf16 hi/lo planes (koct 32..63) ----
  {
    int row = tid >> 6;           // 0..15
    int c0 = (tid & 63)*4;        // 0..252
    float4 v = *(const float4*)(hc + (size_t)(n0+row)*HH + c0);
    *(float4*)&h_pad[row][c0] = v;
    float f[4] = {v.x,v.y,v.z,v.w};
    short h4[4], l4[4];
    #pragma unroll
    for (int j = 0; j < 4; ++j){
      unsigned short hh_ = f2bf(f[j]);
      h4[j] = (short)hh_;
      l4[j] = (short)f2bf(f[j] - bf2f(hh_));
    }
    int koct = 32 + (c0 >> 3), elem = c0 & 7;
    *(short4*)&Xh[koct][row][elem] = *(short4*)h4;
    *(short4*)&Xl[koct][row][elem] = *(short4*)l4;
  }
  // ---- CSR gather: wave wv owns node n0+wv; 48 lanes = 12 w x 4 edge-groups ----
  if (lane < 48){
    int w = lane >> 2, g = lane & 3;
    int node = n0 + wv;
    float acc0 = 0.0f;
    if (g == 0){
      float dv2 = 1.0f/(deg[node] + 1.0f);     // dv*dv
      acc0 = dv2*ring[(size_t)node*RS + s + w];
    }
    int e1 = rowst[node+1];
    for (int e = rowst[node] + g; e < e1; e += 4)
      acc0 += csr_cf[e]*ring[(size_t)csr_src[e]*RS + s + w];
    acc0 += __shfl_xor(acc0, 1, 64);
    acc0 += __shfl_xor(acc0, 2, 64);
    if (g == 0){
      float u = (acc0 + TA) * ((float)TS/(2.0f*TA));
      u = fminf(fmaxf(u, 0.0f), (float)TS - 0.0005f);
      int i = (int)u;
      sidx[wv][w] = i;
      sfrac[wv][w] = u - (float)i;
    }
  }
  __syncthreads();

  // ---- table lerp -> t, split to bf16 hi/lo planes (koct 0..31) ----
  {
    int col = tid & 255;
    int r0 = (tid >> 8)*4;
    int koct = col >> 3, elem = col & 7;
    float tb = ta_b[col];
    #pragma unroll
    for (int rr = 0; rr < 4; ++rr){
      int r = r0 + rr;
      float acc0 = tb;
      #pragma unroll
      for (int w = 0; w < 12; ++w){
        const float* pj = tab + ((size_t)w*(TS+1) + sidx[r][w])*HH + col;
        float v0 = pj[0], v1 = pj[HH];
        acc0 += v0 + sfrac[r][w]*(v1 - v0);
      }
      float tv = acc0 > 0.0f ? acc0 : 0.0f;
      unsigned short hh_ = f2bf(tv);
      Xh[koct][r][elem] = (short)hh_;
      Xl[koct][r][elem] = (short)f2bf(tv - bf2f(hh_));
    }
  }
  __syncthreads();

  // ---- GRU MFMA: wave wv owns col-tile wv (16 cols) x 16 rows, K=512 ----
  f32x4 acc[4];
  #pragma unroll
  for (int g = 0; g < 4; ++g) acc[g] = (f32x4){0.f,0.f,0.f,0.f};

  const int a_row = lane & 15, a_ko = lane >> 4;
  const size_t fbase = (size_t)wv*64 + lane;   // + ks*4096 + g*1024

  short8v b0h[2], b0l[2], b1h[2], b1l[2], b2h[2], b2l[2];

#define LOADB(KS, BUF)                                                        \
  {                                                                           \
    const int G2v = ((KS) < 8) ? 2 : 3;                                       \
    const size_t fb = fbase + (size_t)(KS)*4096;                              \
    b0h[BUF] = *(const short8v*)&wp_hi[fb*8];                                 \
    b0l[BUF] = *(const short8v*)&wp_lo[fb*8];                                 \
    b1h[BUF] = *(const short8v*)&wp_hi[(fb + 1024)*8];                        \
    b1l[BUF] = *(const short8v*)&wp_lo[(fb + 1024)*8];                        \
    b2h[BUF] = *(const short8v*)&wp_hi[(fb + (size_t)G2v*1024)*8];            \
    b2l[BUF] = *(const short8v*)&wp_lo[(fb + (size_t)G2v*1024)*8];            \
  }

  LOADB(0, 0)
  #pragma unroll
  for (int ks = 0; ks < 16; ++ks){
    const int cur = ks & 1, nxt = cur ^ 1;
    if (ks < 15) LOADB(ks+1, nxt)
    short8v ah = *(const short8v*)&Xh[ks*4 + a_ko][a_row][0];
    short8v al = *(const short8v*)&Xl[ks*4 + a_ko][a_row][0];
    const int G2 = (ks < 8) ? 2 : 3;
    acc[0]  = __builtin_amdgcn_mfma_f32_16x16x32_bf16(ah, b0h[cur], acc[0], 0,0,0);
    acc[0]  = __builtin_amdgcn_mfma_f32_16x16x32_bf16(al, b0h[cur], acc[0], 0,0,0);
    acc[0]  = __builtin_amdgcn_mfma_f32_16x16x32_bf16(ah, b0l[cur], acc[0], 0,0,0);
    acc[1]  = __builtin_amdgcn_mfma_f32_16x16x32_bf16(ah, b1h[cur], acc[1], 0,0,0);
    acc[1]  = __builtin_amdgcn_mfma_f32_16x16x32_bf16(al, b1h[cur], acc[1], 0,0,0);
    acc[1]  = __builtin_amdgcn_mfma_f32_16x16x32_bf16(ah, b1l[cur], acc[1], 0,0,0);
    acc[G2] = __builtin_amdgcn_mfma_f32_16x16x32_bf16(ah, b2h[cur], acc[G2], 0,0,0);
    acc[G2] = __builtin_amdgcn_mfma_f32_16x16x32_bf16(al, b2h[cur], acc[G2], 0,0,0);
    acc[G2] = __builtin_amdgcn_mfma_f32_16x16x32_bf16(ah, b2l[cur], acc[G2], 0,0,0);
  }
#undef LOADB
  __syncthreads();

  // ---- epilogue: gates + h' -> global hnb + h_pad (reused for pred) ----
  {
    const int ecl  = lane & 15;
    const int erow = (lane >> 4)*4;
    const int col  = wv*16 + ecl;
    float br  = b_ih[col]        + b_hh[col];
    float bz  = b_ih[col + HH]   + b_hh[col + HH];
    float bxn = b_ih[col + 2*HH];
    float bhn = b_hh[col + 2*HH];
    #pragma unroll
    for (int q = 0; q < 4; ++q){
      int row = erow + q;
      float r = fast_sigmoid(acc[0][q] + br);
      float z = fast_sigmoid(acc[1][q] + bz);
      float n = fast_tanh(acc[2][q] + bxn + r*(acc[3][q] + bhn));
      float hv = h_pad[row][col];
      float hp = (1.0f - z)*n + z*hv;
      hnb[(size_t)(n0+row)*HH + col] = hp;
      h_pad[row][col] = hp;
    }
  }
  __syncthreads();

  // ---- pred: wave wv owns row wv; h' . out_w + out_b -> out, ring ----
  {
    int c0 = lane*4;
    float4 hv = *(const float4*)&h_pad[wv][c0];
    float4 w4 = *(const float4*)(out_w + c0);
    float sacc = hv.x*w4.x + hv.y*w4.y + hv.z*w4.z + hv.w*w4.w;
    sacc += __shfl_xor(sacc, 1, 64);
    sacc += __shfl_xor(sacc, 2, 64);
    sacc += __shfl_xor(sacc, 4, 64);
    sacc += __shfl_xor(sacc, 8, 64);
    sacc += __shfl_xor(sacc, 16, 64);
    sacc += __shfl_xor(sacc, 32, 64);
    if (lane == 0){
      float pv = sacc + out_b[0];
      out[(size_t)(n0+wv)*PP + s] = pv;
      ring[(size_t)(n0+wv)*RS + 12 + s] = pv;
    }
  }
}

// ---------------- launcher ----------------

extern "C" void kernel_launch(void* const* d_in, const int* in_sizes, int n_in,
                              void* d_out, int out_size, void* d_ws, size_t ws_size,
                              hipStream_t stream){
  const float* x     = (const float*)d_in[0];
  const int*   ei    = (const int*)  d_in[1];
  const float* ew    = (const float*)d_in[2];
  const float* gcn_w = (const float*)d_in[3];
  const float* ta_w  = (const float*)d_in[4];
  const float* ta_b  = (const float*)d_in[5];
  const float* w_ih  = (const float*)d_in[6];
  const float* w_hh  = (const float*)d_in[7];
  const float* b_ih  = (const float*)d_in[8];
  const float* b_hh  = (const float*)d_in[9];
  const float* out_w = (const float*)d_in[10];
  const float* out_b = (const float*)d_in[11];
  float* out = (float*)d_out;

  char* p = (char*)d_ws;
  float* tab     = (float*)p; p += (size_t)12*(TS+1)*HH*4; // 2.37 MB
  int*   keys    = (int*)p;   p += (size_t)HS*4;
  int*   midx    = (int*)p;   p += (size_t)HS*4;
  int*   wsrc    = (int*)p;   p += (size_t)EE*4;
  int*   wdst    = (int*)p;   p += (size_t)EE*4;
  float* wwt     = (float*)p; p += (size_t)EE*4;
  int*   csr_src = (int*)p;   p += (size_t)EE*4;
  float* csr_cf  = (float*)p; p += (size_t)EE*4;
  float* deg     = (float*)p; p += (size_t)NN*4;
  int*   cnt     = (int*)p;   p += (size_t)NN*4;
  int*   fill    = (int*)p;   p += (size_t)NN*4;
  int*   rowst   = (int*)p;   p += (size_t)(NN+64)*4;
  int*   count   = (int*)p;   p += 256;
  float* ring    = (float*)p; p += (size_t)NN*RS*4;
  float* hA      = (float*)p; p += (size_t)NN*HH*4;
  float* hB      = (float*)p; p += (size_t)NN*HH*4;
  short* wp_hi   = (short*)p; p += (size_t)16*4*16*64*8*2; // 1 MB
  short* wp_lo   = (short*)p; p += (size_t)16*4*16*64*8*2; // 1 MB

  k_init   <<<(NN*HH)/256, 256, 0, stream>>>(x, keys, midx, deg, cnt, ring, hA, count);
  k_insert <<<EE/256, 256, 0, stream>>>(ei, keys, midx);
  k_compact<<<EE/256, 256, 0, stream>>>(ei, ew, keys, midx, wsrc, wdst, wwt, deg, cnt, count);
  k_scan   <<<1, 1024, 0, stream>>>(cnt, rowst, fill);
  k_scatter<<<EE/256, 256, 0, stream>>>(wsrc, wdst, wwt, deg, fill, csr_src, csr_cf, count);
  k_wpack  <<<256, 256, 0, stream>>>(w_ih, w_hh, wp_hi, wp_lo);
  k_tab    <<<dim3(HH/64, (TS+64)/64, WW), 256, 0, stream>>>(gcn_w, ta_w, tab);

  for (int s = 0; s < PP; ++s){
    const float* hc  = (s & 1) ? hB : hA;
    float*       hnb = (s & 1) ? hA : hB;
    k_step<<<NN/16, 1024, 0, stream>>>(rowst, csr_src, csr_cf, deg, ring, tab,
                                       ta_b, hc, hnb, wp_hi, wp_lo,
                                       b_ih, b_hh, out_w, out_b, out, s);
  }
}

// Round 10
// 296.248 us; speedup vs baseline: 1.9164x; 1.2292x over previous
//
#include <hip/hip_runtime.h>
#include <math.h>

#define NN 4096
#define WW 12
#define HH 256
#define PP 10
#define EE 131072
#define HS 262144
#define HMASK (HS-1)
#define TS 192           // table intervals (193 sample points) -> 2.37 MB, L2-resident
#define TA 8.0f          // table half-domain: a in [-TA, TA]
#define RS 22            // ring stride: 12 init cols + 10 pred cols (append, no overwrite)

typedef __attribute__((ext_vector_type(8))) _Float16 half8v;  // 8 x fp16 (A/B frag)
typedef __attribute__((ext_vector_type(4))) _Float16 half4v;
typedef __attribute__((ext_vector_type(4))) float f32x4;      // C/D frag

__device__ __forceinline__ float fast_tanh(float x){
  float e = __expf(2.0f*x);
  return 1.0f - 2.0f/(e+1.0f);   // exact identity (e^2x-1)/(e^2x+1)
}
__device__ __forceinline__ float fast_sigmoid(float x){
  return 1.0f/(1.0f+__expf(-x));
}

// ---------------- setup kernels ----------------

__global__ void k_init(const float* __restrict__ x, int* keys, int* midx,
                       float* deg, int* cnt, float* ring, float* hA, int* count){
  int i = blockIdx.x*256 + threadIdx.x;
  if (i < HS){ keys[i] = -1; midx[i] = -1; }
  if (i < NN){ deg[i] = 0.0f; cnt[i] = 0; }
  if (i < NN*WW){ int n = i/WW, w = i - n*WW; ring[n*RS + w] = x[i]; }
  if (i < NN*HH) hA[i] = 0.0f;
  if (i == 0) *count = 0;
}

// dedupe: numpy fancy assignment => last (max-index) edge wins per (src,dst)
__global__ void k_insert(const int* __restrict__ ei, int* keys, int* midx){
  int e = blockIdx.x*256 + threadIdx.x;
  if (e >= EE) return;
  int key = ei[e]*NN + ei[EE+e];
  unsigned h = (((unsigned)key)*2654435761u >> 14) & HMASK;
  for(;;){
    int k = keys[h];
    if (k == key){ atomicMax(&midx[h], e); return; }
    if (k == -1){
      int old = atomicCAS(&keys[h], -1, key);
      if (old == -1 || old == key){ atomicMax(&midx[h], e); return; }
    }
    h = (h+1) & HMASK;
  }
}

__global__ void k_compact(const int* __restrict__ ei, const float* __restrict__ ew,
                          const int* __restrict__ keys, const int* __restrict__ midx,
                          int* wsrc, int* wdst, float* wwt,
                          float* deg, int* cnt, int* count){
  int e = blockIdx.x*256 + threadIdx.x;
  if (e >= EE) return;
  int src = ei[e], dst = ei[EE+e];
  int key = src*NN + dst;
  unsigned h = (((unsigned)key)*2654435761u >> 14) & HMASK;
  while (keys[h] != key) h = (h+1) & HMASK;
  if (midx[h] == e){            // this edge is the winner for (src,dst)
    int p = atomicAdd(count, 1);
    wsrc[p] = src; wdst[p] = dst; wwt[p] = ew[e];
    atomicAdd(&deg[src], ew[e]);   // deg = row-sum of deduped adj (self-loop +1 later)
    atomicAdd(&cnt[dst], 1);       // CSR histogram keyed by dst (L uses adj^T)
  }
}

__global__ __launch_bounds__(1024) void k_scan(const int* __restrict__ cnt,
                                               int* row_start, int* fill){
  __shared__ int sd[NN];
  int tid = threadIdx.x;
  for (int i = tid; i < NN; i += 1024) sd[i] = cnt[i];
  __syncthreads();
  for (int off = 1; off < NN; off <<= 1){
    int v[4];
    #pragma unroll
    for (int r = 0; r < 4; ++r){
      int i = tid + r*1024;
      v[r] = (i >= off) ? sd[i-off] : 0;
    }
    __syncthreads();
    #pragma unroll
    for (int r = 0; r < 4; ++r) sd[tid + r*1024] += v[r];
    __syncthreads();
  }
  for (int i = tid; i < NN; i += 1024){
    int incl = sd[i];
    row_start[i+1] = incl;
    fill[i] = incl - cnt[i];   // exclusive prefix = scatter cursor
  }
  if (tid == 0) row_start[0] = 0;
}

// scatter + inline coef = wwt * d[src] * d[dst], d = 1/sqrt(deg+1)
__global__ void k_scatter(const int* __restrict__ wsrc, const int* __restrict__ wdst,
                          const float* __restrict__ wwt, const float* __restrict__ deg,
                          int* fill, int* csr_src, float* csr_cf,
                          const int* __restrict__ count){
  int p = blockIdx.x*256 + threadIdx.x;
  if (p >= *count) return;
  int s = wsrc[p], d = wdst[p];
  float c = wwt[p] * (1.0f/sqrtf(deg[s]+1.0f)) * (1.0f/sqrtf(deg[d]+1.0f));
  int pos = atomicAdd(&fill[d], 1);
  csr_src[pos] = s;
  csr_cf[pos] = c;
}

// table build: tab[w][s][h] = sum_c tanh(a_s*gw[c]) * ta_w[w*256+c, h]
__global__ __launch_bounds__(256) void k_tab(const float* __restrict__ gcn_w,
                                             const float* __restrict__ ta_w,
                                             float* __restrict__ tab){
  __shared__ float As[32][64];
  __shared__ float Bs[32][64];
  __shared__ float gws[256];
  int tid = threadIdx.x;
  int n0 = blockIdx.x*64;        // h tile
  int m0 = blockIdx.y*64;        // sample tile
  int w  = blockIdx.z;
  gws[tid] = gcn_w[tid];
  __syncthreads();
  float acc[4][4] = {};
  int tm = tid >> 4, tn = tid & 15;
  const float astep = 2.0f*TA/TS;
  for (int k0 = 0; k0 < 256; k0 += 32){
    #pragma unroll
    for (int r = 0; r < 2; ++r){
      int f = tid + r*256;
      int kk = f >> 4, n4 = (f & 15)*4;
      *(float4*)&Bs[kk][n4] = *(const float4*)&ta_w[(w*256 + k0+kk)*HH + n0 + n4];
    }
    {
      int kk = tid >> 3;
      int mb = (tid & 7)*8;
      float gw = gws[k0 + kk];
      #pragma unroll
      for (int i2 = 0; i2 < 8; ++i2){
        float a = -TA + (float)(m0 + mb + i2)*astep;
        As[kk][mb+i2] = fast_tanh(a*gw);
      }
    }
    __syncthreads();
    #pragma unroll
    for (int kk = 0; kk < 32; ++kk){
      float4 a4 = *(float4*)&As[kk][tm*4];
      float4 b4 = *(float4*)&Bs[kk][tn*4];
      float a[4] = {a4.x,a4.y,a4.z,a4.w};
      float b[4] = {b4.x,b4.y,b4.z,b4.w};
      #pragma unroll
      for (int i = 0; i < 4; ++i)
        #pragma unroll
        for (int j = 0; j < 4; ++j)
          acc[i][j] = fmaf(a[i], b[j], acc[i][j]);
    }
    __syncthreads();
  }
  #pragma unroll
  for (int i = 0; i < 4; ++i){
    int row = m0 + tm*4 + i;
    if (row <= TS){
      #pragma unroll
      for (int j = 0; j < 4; ++j)
        tab[((size_t)w*(TS+1) + row)*HH + n0 + tn*4 + j] = acc[i][j];
    }
  }
}

// pack GRU weights into MFMA B-fragment order, SINGLE fp16 plane (run once).
// groups g: 0=r, 1=z, 2=xn (K 0..255), 3=hn (K 256..511).
// layout: [ks(16)][g(4)][ct(16)][lane(64)][8 halfs]
__global__ void k_wpack(const float* __restrict__ w_ih, const float* __restrict__ w_hh,
                        _Float16* __restrict__ wp){
  int idx = blockIdx.x*256 + threadIdx.x;       // 65536 fragment-octets
  int lane = idx & 63;
  int rest = idx >> 6;
  int ct = rest & 15; rest >>= 4;
  int g  = rest & 3;
  int ks = rest >> 2;
  int col = ct*16 + (lane & 15);
  int kb  = ks*32 + (lane >> 4)*8;
  _Float16 w8[8];
  #pragma unroll
  for (int j = 0; j < 8; ++j){
    int k = kb + j;
    float v;
    if      (g == 0) v = (k < 256) ? w_ih[col*HH + k]        : w_hh[col*HH + k - 256];
    else if (g == 1) v = (k < 256) ? w_ih[(256+col)*HH + k]  : w_hh[(256+col)*HH + k - 256];
    else if (g == 2) v = (k < 256) ? w_ih[(512+col)*HH + k]  : 0.0f;
    else             v = (k < 256) ? 0.0f                    : w_hh[(512+col)*HH + k - 256];
    w8[j] = (_Float16)v;              // RNE fp32->fp16, err 2^-12 rel
  }
  *(half8v*)&wp[(size_t)idx*8] = *(half8v*)w8;
}

// ---------------- the per-step kernel ----------------
// One dispatch per step; 256 blocks x 1024 threads; block owns nodes
// [16b,16b+16) END-TO-END. A=[t|h] split to fp16 hi/lo planes (A stays
// fp32-exact); W is a SINGLE fp16 plane -> per-(ks,ct) B traffic is
// 3 frags (48B/lane) instead of 6, halving the L2 weight stream that
// R9's analysis identified as the wall. 2 MFMAs per group: Ah*B + Al*B.
__global__ __launch_bounds__(1024, 4) void k_step(
    const int* __restrict__ rowst, const int* __restrict__ csr_src,
    const float* __restrict__ csr_cf, const float* __restrict__ deg,
    float* __restrict__ ring, const float* __restrict__ tab,
    const float* __restrict__ ta_b,
    const float* __restrict__ hc, float* __restrict__ hnb,
    const _Float16* __restrict__ wp,
    const float* __restrict__ b_ih, const float* __restrict__ b_hh,
    const float* __restrict__ out_w, const float* __restrict__ out_b,
    float* __restrict__ out, int s){

  __shared__ __align__(16) _Float16 Xh[64][17][8];   // 17.4 KB, koct stride 272B
  __shared__ __align__(16) _Float16 Xl[64][17][8];
  __shared__ __align__(16) float h_pad[16][260];     // fp32 h for epilogue + pred
  __shared__ int   sidx[16][12];
  __shared__ float sfrac[16][12];

  const int tid = threadIdx.x;
  const int n0 = blockIdx.x*16;
  const int wv = tid >> 6, lane = tid & 63;

  // ---- stage hc -> LDS fp32 + fp16 hi/lo planes (koct 32..63) ----
  {
    int row = tid >> 6;           // 0..15
    int c0 = (tid & 63)*4;        // 0..252
    float4 v = *(const float4*)(hc + (size_t)(n0+row)*HH + c0);
    *(float4*)&h_pad[row][c0] = v;
    float f[4] = {v.x,v.y,v.z,v.w};
    _Float16 h4[4], l4[4];
    #pragma unroll
    for (int j = 0; j < 4; ++j){
      h4[j] = (_Float16)f[j];
      l4[j] = (_Float16)(f[j] - (float)h4[j]);
    }
    int koct = 32 + (c0 >> 3), elem = c0 & 7;
    *(half4v*)&Xh[koct][row][elem] = *(half4v*)h4;
    *(half4v*)&Xl[koct][row][elem] = *(half4v*)l4;
  }
  // ---- CSR gather: wave wv owns node n0+wv; 48 lanes = 12 w x 4 edge-groups ----
  if (lane < 48){
    int w = lane >> 2, g = lane & 3;
    int node = n0 + wv;
    float acc0 = 0.0f;
    if (g == 0){
      float dv2 = 1.0f/(deg[node] + 1.0f);     // dv*dv
      acc0 = dv2*ring[(size_t)node*RS + s + w];
    }
    int e1 = rowst[node+1];
    for (int e = rowst[node] + g; e < e1; e += 4)
      acc0 += csr_cf[e]*ring[(size_t)csr_src[e]*RS + s + w];
    acc0 += __shfl_xor(acc0, 1, 64);
    acc0 += __shfl_xor(acc0, 2, 64);
    if (g == 0){
      float u = (acc0 + TA) * ((float)TS/(2.0f*TA));
      u = fminf(fmaxf(u, 0.0f), (float)TS - 0.0005f);
      int i = (int)u;
      sidx[wv][w] = i;
      sfrac[wv][w] = u - (float)i;
    }
  }
  __syncthreads();

  // ---- table lerp -> t, split to fp16 hi/lo planes (koct 0..31) ----
  {
    int col = tid & 255;
    int r0 = (tid >> 8)*4;
    int koct = col >> 3, elem = col & 7;
    float tb = ta_b[col];
    #pragma unroll
    for (int rr = 0; rr < 4; ++rr){
      int r = r0 + rr;
      float acc0 = tb;
      #pragma unroll
      for (int w = 0; w < 12; ++w){
        const float* pj = tab + ((size_t)w*(TS+1) + sidx[r][w])*HH + col;
        float v0 = pj[0], v1 = pj[HH];
        acc0 += v0 + sfrac[r][w]*(v1 - v0);
      }
      float tv = acc0 > 0.0f ? acc0 : 0.0f;
      _Float16 hh_ = (_Float16)tv;
      Xh[koct][r][elem] = hh_;
      Xl[koct][r][elem] = (_Float16)(tv - (float)hh_);
    }
  }
  __syncthreads();

  // ---- GRU MFMA: wave wv owns col-tile wv (16 cols) x 16 rows, K=512 ----
  f32x4 acc[4];
  #pragma unroll
  for (int g = 0; g < 4; ++g) acc[g] = (f32x4){0.f,0.f,0.f,0.f};

  const int a_row = lane & 15, a_ko = lane >> 4;
  const size_t fbase = (size_t)wv*64 + lane;   // + ks*4096 + g*1024

  half8v b0[2], b1[2], b2[2];

#define LOADB(KS, BUF)                                                        \
  {                                                                           \
    const int G2v = ((KS) < 8) ? 2 : 3;                                       \
    const size_t fb = fbase + (size_t)(KS)*4096;                              \
    b0[BUF] = *(const half8v*)&wp[fb*8];                                      \
    b1[BUF] = *(const half8v*)&wp[(fb + 1024)*8];                             \
    b2[BUF] = *(const half8v*)&wp[(fb + (size_t)G2v*1024)*8];                 \
  }

  LOADB(0, 0)
  #pragma unroll
  for (int ks = 0; ks < 16; ++ks){
    const int cur = ks & 1, nxt = cur ^ 1;
    if (ks < 15) LOADB(ks+1, nxt)
    half8v ah = *(const half8v*)&Xh[ks*4 + a_ko][a_row][0];
    half8v al = *(const half8v*)&Xl[ks*4 + a_ko][a_row][0];
    const int G2 = (ks < 8) ? 2 : 3;
    acc[0]  = __builtin_amdgcn_mfma_f32_16x16x32_f16(ah, b0[cur], acc[0], 0,0,0);
    acc[0]  = __builtin_amdgcn_mfma_f32_16x16x32_f16(al, b0[cur], acc[0], 0,0,0);
    acc[1]  = __builtin_amdgcn_mfma_f32_16x16x32_f16(ah, b1[cur], acc[1], 0,0,0);
    acc[1]  = __builtin_amdgcn_mfma_f32_16x16x32_f16(al, b1[cur], acc[1], 0,0,0);
    acc[G2] = __builtin_amdgcn_mfma_f32_16x16x32_f16(ah, b2[cur], acc[G2], 0,0,0);
    acc[G2] = __builtin_amdgcn_mfma_f32_16x16x32_f16(al, b2[cur], acc[G2], 0,0,0);
  }
#undef LOADB
  __syncthreads();

  // ---- epilogue: gates + h' -> global hnb + h_pad (reused for pred) ----
  {
    const int ecl  = lane & 15;
    const int erow = (lane >> 4)*4;
    const int col  = wv*16 + ecl;
    float br  = b_ih[col]        + b_hh[col];
    float bz  = b_ih[col + HH]   + b_hh[col + HH];
    float bxn = b_ih[col + 2*HH];
    float bhn = b_hh[col + 2*HH];
    #pragma unroll
    for (int q = 0; q < 4; ++q){
      int row = erow + q;
      float r = fast_sigmoid(acc[0][q] + br);
      float z = fast_sigmoid(acc[1][q] + bz);
      float n = fast_tanh(acc[2][q] + bxn + r*(acc[3][q] + bhn));
      float hv = h_pad[row][col];
      float hp = (1.0f - z)*n + z*hv;
      hnb[(size_t)(n0+row)*HH + col] = hp;
      h_pad[row][col] = hp;
    }
  }
  __syncthreads();

  // ---- pred: wave wv owns row wv; h' . out_w + out_b -> out, ring ----
  {
    int c0 = lane*4;
    float4 hv = *(const float4*)&h_pad[wv][c0];
    float4 w4 = *(const float4*)(out_w + c0);
    float sacc = hv.x*w4.x + hv.y*w4.y + hv.z*w4.z + hv.w*w4.w;
    sacc += __shfl_xor(sacc, 1, 64);
    sacc += __shfl_xor(sacc, 2, 64);
    sacc += __shfl_xor(sacc, 4, 64);
    sacc += __shfl_xor(sacc, 8, 64);
    sacc += __shfl_xor(sacc, 16, 64);
    sacc += __shfl_xor(sacc, 32, 64);
    if (lane == 0){
      float pv = sacc + out_b[0];
      out[(size_t)(n0+wv)*PP + s] = pv;
      ring[(size_t)(n0+wv)*RS + 12 + s] = pv;
    }
  }
}

// ---------------- launcher ----------------

extern "C" void kernel_launch(void* const* d_in, const int* in_sizes, int n_in,
                              void* d_out, int out_size, void* d_ws, size_t ws_size,
                              hipStream_t stream){
  const float* x     = (const float*)d_in[0];
  const int*   ei    = (const int*)  d_in[1];
  const float* ew    = (const float*)d_in[2];
  const float* gcn_w = (const float*)d_in[3];
  const float* ta_w  = (const float*)d_in[4];
  const float* ta_b  = (const float*)d_in[5];
  const float* w_ih  = (const float*)d_in[6];
  const float* w_hh  = (const float*)d_in[7];
  const float* b_ih  = (const float*)d_in[8];
  const float* b_hh  = (const float*)d_in[9];
  const float* out_w = (const float*)d_in[10];
  const float* out_b = (const float*)d_in[11];
  float* out = (float*)d_out;

  char* p = (char*)d_ws;
  float*    tab     = (float*)p;    p += (size_t)12*(TS+1)*HH*4; // 2.37 MB
  int*      keys    = (int*)p;      p += (size_t)HS*4;
  int*      midx    = (int*)p;      p += (size_t)HS*4;
  int*      wsrc    = (int*)p;      p += (size_t)EE*4;
  int*      wdst    = (int*)p;      p += (size_t)EE*4;
  float*    wwt     = (float*)p;    p += (size_t)EE*4;
  int*      csr_src = (int*)p;      p += (size_t)EE*4;
  float*    csr_cf  = (float*)p;    p += (size_t)EE*4;
  float*    deg     = (float*)p;    p += (size_t)NN*4;
  int*      cnt     = (int*)p;      p += (size_t)NN*4;
  int*      fill    = (int*)p;      p += (size_t)NN*4;
  int*      rowst   = (int*)p;      p += (size_t)(NN+64)*4;
  int*      count   = (int*)p;      p += 256;
  float*    ring    = (float*)p;    p += (size_t)NN*RS*4;
  float*    hA      = (float*)p;    p += (size_t)NN*HH*4;
  float*    hB      = (float*)p;    p += (size_t)NN*HH*4;
  _Float16* wp      = (_Float16*)p; p += (size_t)16*4*16*64*8*2; // 1 MB

  k_init   <<<(NN*HH)/256, 256, 0, stream>>>(x, keys, midx, deg, cnt, ring, hA, count);
  k_insert <<<EE/256, 256, 0, stream>>>(ei, keys, midx);
  k_compact<<<EE/256, 256, 0, stream>>>(ei, ew, keys, midx, wsrc, wdst, wwt, deg, cnt, count);
  k_scan   <<<1, 1024, 0, stream>>>(cnt, rowst, fill);
  k_scatter<<<EE/256, 256, 0, stream>>>(wsrc, wdst, wwt, deg, fill, csr_src, csr_cf, count);
  k_wpack  <<<256, 256, 0, stream>>>(w_ih, w_hh, wp);
  k_tab    <<<dim3(HH/64, (TS+64)/64, WW), 256, 0, stream>>>(gcn_w, ta_w, tab);

  for (int s = 0; s < PP; ++s){
    const float* hc  = (s & 1) ? hB : hA;
    float*       hnb = (s & 1) ? hA : hB;
    k_step<<<NN/16, 1024, 0, stream>>>(rowst, csr_src, csr_cf, deg, ring, tab,
                                       ta_b, hc, hnb, wp,
                                       b_ih, b_hh, out_w, out_b, out, s);
  }
}